// Round 11
// baseline (164.666 us; speedup 1.0000x reference)
//
#include <hip/hip_runtime.h>

#define BB 16384
#define CC 10
#define KK 20
#define DD 128
#define NBLOCKS (BB / 8)   // 2048

// fast, accurate-enough log sigmoid: logsig(x) = min(x,0) - log(1 + exp(-|x|))
__device__ __forceinline__ float lsg(float x) {
    return fminf(x, 0.0f) - __logf(1.0f + __expf(-fabsf(x)));
}

// butterfly add via ds_swizzle (xor pattern). MASK is ICE.
template <int MASK>
__device__ __forceinline__ float swz_add(float v) {
    int r = __builtin_amdgcn_ds_swizzle(__float_as_int(v), MASK);
    return v + __int_as_float(r);
}

__device__ __forceinline__ float dot4(float4 a, float4 b) {
    return a.x * b.x + a.y * b.y + a.z * b.z + a.w * b.w;
}
__device__ __forceinline__ void add4(float4& a, float4 b) {
    a.x += b.x; a.y += b.y; a.z += b.z; a.w += b.w;
}

// 32 lanes per b, 2 b per wave, 8 b per block -> 2048 blocks.
// Ticket is memset to 0 on the stream before every launch (graph-safe), so
// (old+1 == NBLOCKS) is a true last-arrival test — R9/R10 failed because the
// 0xAA-poisoned ticket (682 mod 2048) made the trigger fire at arrival 1366,
// reducing 682 still-poison partials (result scaled x0.667 — matched absmax).
// Partials are published/read with AGENT-scope atomics (cross-XCD, G16).
__global__ __launch_bounds__(256) void w2v_loss_kernel(
    const int*   __restrict__ context,    // [B, C]
    const int*   __restrict__ target,     // [B]
    const int*   __restrict__ negs,       // [B, K]
    const float* __restrict__ embW,       // [V, D]
    const float* __restrict__ ctxW,       // [V, D]
    float*       __restrict__ block_part, // [NBLOCKS] in d_ws
    unsigned int* __restrict__ ticket,    // 1 uint in d_ws (zeroed pre-launch)
    float*       __restrict__ out
) {
    const int tid   = threadIdx.x;
    const int wave  = tid >> 6;
    const int lane  = tid & 63;
    const int group = lane >> 5;          // 2 groups of 32 lanes per wave
    const int gl    = lane & 31;          // lane owns one float4 of the 512 B row
    const int bl    = wave * 2 + group;   // 0..7 local batch element
    const int b0    = blockIdx.x * 8;

    __shared__ int s_ctx[8 * CC];
    __shared__ int s_tgt[8];
    __shared__ int s_neg[8 * KK];
    __shared__ float sp[4];
    __shared__ unsigned int is_last;

    if (tid < 8 * CC) s_ctx[tid] = context[b0 * CC + tid];
    if (tid < 8)      s_tgt[tid] = target[b0 + tid];
    if (tid < 8 * KK) s_neg[tid] = negs[b0 * KK + tid];
    __syncthreads();

    const float4* ctxW4 = reinterpret_cast<const float4*>(ctxW);
    const float4* embW4 = reinterpret_cast<const float4*>(embW);

    // ---- context mean ----
    float4 acc = make_float4(0.f, 0.f, 0.f, 0.f);
    #pragma unroll
    for (int c = 0; c < CC; ++c) {
        const int row = s_ctx[bl * CC + c] * (DD / 4);
        add4(acc, ctxW4[row + gl]);
    }
    const float inv = 1.0f / CC;
    acc.x *= inv; acc.y *= inv; acc.z *= inv; acc.w *= inv;

    // ---- target dot partial ----
    const int trow = s_tgt[bl] * (DD / 4);
    float pd = dot4(acc, embW4[trow + gl]);

    // ---- negative dot partials ----
    float nd[KK];
    #pragma unroll
    for (int k = 0; k < KK; ++k) {
        const int row = s_neg[bl * KK + k] * (DD / 4);
        nd[k] = dot4(acc, ctxW4[row + gl]);
    }

    // ---- reduce over the 32 lanes: xor 1,2,4,8,16 via ds_swizzle ----
    pd = swz_add<0x041F>(pd);
    #pragma unroll
    for (int k = 0; k < KK; ++k) nd[k] = swz_add<0x041F>(nd[k]);
    pd = swz_add<0x081F>(pd);
    #pragma unroll
    for (int k = 0; k < KK; ++k) nd[k] = swz_add<0x081F>(nd[k]);
    pd = swz_add<0x101F>(pd);
    #pragma unroll
    for (int k = 0; k < KK; ++k) nd[k] = swz_add<0x101F>(nd[k]);
    pd = swz_add<0x201F>(pd);
    #pragma unroll
    for (int k = 0; k < KK; ++k) nd[k] = swz_add<0x201F>(nd[k]);
    pd = swz_add<0x401F>(pd);
    #pragma unroll
    for (int k = 0; k < KK; ++k) nd[k] = swz_add<0x401F>(nd[k]);

    // ---- per-b score (2 b's of this wave in parallel) ----
    float score = lsg(pd);
    #pragma unroll
    for (int k = 0; k < KK; ++k) score += lsg(-nd[k]);

    // ---- combine the 2 groups of this wave ----
    float s = score + __shfl_xor(score, 32, 64);

    if (lane == 0) sp[wave] = s;
    __syncthreads();

    // ---- publish partial (agent-scope), take ticket ----
    if (tid == 0) {
        const float psum = sp[0] + sp[1] + sp[2] + sp[3];
        __hip_atomic_store(&block_part[blockIdx.x], psum,
                           __ATOMIC_RELEASE, __HIP_MEMORY_SCOPE_AGENT);
        const unsigned int old = __hip_atomic_fetch_add(
            ticket, 1u, __ATOMIC_ACQ_REL, __HIP_MEMORY_SCOPE_AGENT);
        is_last = (old + 1u == (unsigned int)NBLOCKS);
    }
    __syncthreads();

    // ---- true last block: fixed-order final reduction (agent-scope loads) ----
    if (is_last) {
        float t = 0.f;
        for (int i = tid; i < NBLOCKS; i += 256)
            t += __hip_atomic_load(&block_part[i],
                                   __ATOMIC_RELAXED, __HIP_MEMORY_SCOPE_AGENT);
        #pragma unroll
        for (int off = 32; off; off >>= 1) t += __shfl_xor(t, off, 64);
        if (lane == 0) sp[wave] = t;
        __syncthreads();
        if (tid == 0)
            out[0] = -(sp[0] + sp[1] + sp[2] + sp[3]) * (1.0f / (float)BB);
    }
}

extern "C" void kernel_launch(void* const* d_in, const int* in_sizes, int n_in,
                              void* d_out, int out_size, void* d_ws, size_t ws_size,
                              hipStream_t stream) {
    const int*   context = (const int*)d_in[0];
    const int*   target  = (const int*)d_in[1];
    const int*   negs    = (const int*)d_in[2];
    const float* embW    = (const float*)d_in[3];
    const float* ctxW    = (const float*)d_in[4];
    float* out = (float*)d_out;

    float*        block_part = (float*)d_ws;                 // 2048 floats
    unsigned int* ticket     = (unsigned int*)((char*)d_ws + NBLOCKS * sizeof(float));

    // zero the ticket every call (graph-safe async memset on the stream):
    // makes the last-arrival test exact regardless of prior d_ws contents.
    hipMemsetAsync(ticket, 0, sizeof(unsigned int), stream);

    w2v_loss_kernel<<<NBLOCKS, 256, 0, stream>>>(
        context, target, negs, embW, ctxW, block_part, ticket, out);
}

// Round 12
// 54.265 us; speedup vs baseline: 3.0345x; 3.0345x over previous
//
#include <hip/hip_runtime.h>

#define BB 16384
#define CC 10
#define KK 20
#define DD 128
#define NBLOCKS (BB / 8)   // 2048

// fast, accurate-enough log sigmoid: logsig(x) = min(x,0) - log(1 + exp(-|x|))
__device__ __forceinline__ float lsg(float x) {
    return fminf(x, 0.0f) - __logf(1.0f + __expf(-fabsf(x)));
}

// butterfly add via ds_swizzle (xor pattern). MASK is ICE.
template <int MASK>
__device__ __forceinline__ float swz_add(float v) {
    int r = __builtin_amdgcn_ds_swizzle(__float_as_int(v), MASK);
    return v + __int_as_float(r);
}

__device__ __forceinline__ float dot4(float4 a, float4 b) {
    return a.x * b.x + a.y * b.y + a.z * b.z + a.w * b.w;
}
__device__ __forceinline__ void add4(float4& a, float4 b) {
    a.x += b.x; a.y += b.y; a.z += b.z; a.w += b.w;
}

// 32 lanes per b, 2 b per wave, 8 b per block -> 2048 blocks.
// Last-arrival block reduces all partials in FIXED order (deterministic).
// Cross-XCD handoff: RELAXED agent-scope atomics only (sc-bit accesses to the
// coherence point, NO buffer_inv/buffer_wbl2). R11 used REL/ACQ_REL semantics
// whose per-block whole-L2 invalidate/writeback thrashed ctxW for co-resident
// blocks (40.7 -> 173 us, FETCH unchanged). Ordering "partial visible before
// ticket bump" is enforced by s_waitcnt vmcnt(0) between the two relaxed ops
// (manual release without the L2 flush; the partial store is write-through).
// Ticket is memset to 0 pre-launch (graph-safe) so old+1==NBLOCKS is exact.
__global__ __launch_bounds__(256) void w2v_loss_kernel(
    const int*   __restrict__ context,    // [B, C]
    const int*   __restrict__ target,     // [B]
    const int*   __restrict__ negs,       // [B, K]
    const float* __restrict__ embW,       // [V, D]
    const float* __restrict__ ctxW,       // [V, D]
    float*       __restrict__ block_part, // [NBLOCKS] in d_ws
    unsigned int* __restrict__ ticket,    // 1 uint in d_ws (zeroed pre-launch)
    float*       __restrict__ out
) {
    const int tid   = threadIdx.x;
    const int wave  = tid >> 6;
    const int lane  = tid & 63;
    const int group = lane >> 5;          // 2 groups of 32 lanes per wave
    const int gl    = lane & 31;          // lane owns one float4 of the 512 B row
    const int bl    = wave * 2 + group;   // 0..7 local batch element
    const int b0    = blockIdx.x * 8;

    __shared__ int s_ctx[8 * CC];
    __shared__ int s_tgt[8];
    __shared__ int s_neg[8 * KK];
    __shared__ float sp[4];
    __shared__ unsigned int is_last;

    if (tid < 8 * CC) s_ctx[tid] = context[b0 * CC + tid];
    if (tid < 8)      s_tgt[tid] = target[b0 + tid];
    if (tid < 8 * KK) s_neg[tid] = negs[b0 * KK + tid];
    __syncthreads();

    const float4* ctxW4 = reinterpret_cast<const float4*>(ctxW);
    const float4* embW4 = reinterpret_cast<const float4*>(embW);

    // ---- context mean ----
    float4 acc = make_float4(0.f, 0.f, 0.f, 0.f);
    #pragma unroll
    for (int c = 0; c < CC; ++c) {
        const int row = s_ctx[bl * CC + c] * (DD / 4);
        add4(acc, ctxW4[row + gl]);
    }
    const float inv = 1.0f / CC;
    acc.x *= inv; acc.y *= inv; acc.z *= inv; acc.w *= inv;

    // ---- target dot partial ----
    const int trow = s_tgt[bl] * (DD / 4);
    float pd = dot4(acc, embW4[trow + gl]);

    // ---- negative dot partials ----
    float nd[KK];
    #pragma unroll
    for (int k = 0; k < KK; ++k) {
        const int row = s_neg[bl * KK + k] * (DD / 4);
        nd[k] = dot4(acc, ctxW4[row + gl]);
    }

    // ---- reduce over the 32 lanes: xor 1,2,4,8,16 via ds_swizzle ----
    pd = swz_add<0x041F>(pd);
    #pragma unroll
    for (int k = 0; k < KK; ++k) nd[k] = swz_add<0x041F>(nd[k]);
    pd = swz_add<0x081F>(pd);
    #pragma unroll
    for (int k = 0; k < KK; ++k) nd[k] = swz_add<0x081F>(nd[k]);
    pd = swz_add<0x101F>(pd);
    #pragma unroll
    for (int k = 0; k < KK; ++k) nd[k] = swz_add<0x101F>(nd[k]);
    pd = swz_add<0x201F>(pd);
    #pragma unroll
    for (int k = 0; k < KK; ++k) nd[k] = swz_add<0x201F>(nd[k]);
    pd = swz_add<0x401F>(pd);
    #pragma unroll
    for (int k = 0; k < KK; ++k) nd[k] = swz_add<0x401F>(nd[k]);

    // ---- per-b score (2 b's of this wave in parallel) ----
    float score = lsg(pd);
    #pragma unroll
    for (int k = 0; k < KK; ++k) score += lsg(-nd[k]);

    // ---- combine the 2 groups of this wave ----
    float s = score + __shfl_xor(score, 32, 64);

    if (lane == 0) sp[wave] = s;
    __syncthreads();

    // ---- publish partial (relaxed, write-through) -> wait ack -> ticket ----
    if (tid == 0) {
        const float psum = sp[0] + sp[1] + sp[2] + sp[3];
        __hip_atomic_store(&block_part[blockIdx.x], psum,
                           __ATOMIC_RELAXED, __HIP_MEMORY_SCOPE_AGENT);
        // manual release: partial store must reach the coherence point before
        // the ticket bump becomes visible. No buffer_wbl2/inv -> no L2 thrash.
        asm volatile("s_waitcnt vmcnt(0)" ::: "memory");
        const unsigned int old = __hip_atomic_fetch_add(
            ticket, 1u, __ATOMIC_RELAXED, __HIP_MEMORY_SCOPE_AGENT);
        is_last = (old + 1u == (unsigned int)NBLOCKS);
    }
    __syncthreads();

    // ---- true last block: fixed-order final reduction (relaxed loads) ----
    if (is_last) {
        float t = 0.f;
        for (int i = tid; i < NBLOCKS; i += 256)
            t += __hip_atomic_load(&block_part[i],
                                   __ATOMIC_RELAXED, __HIP_MEMORY_SCOPE_AGENT);
        #pragma unroll
        for (int off = 32; off; off >>= 1) t += __shfl_xor(t, off, 64);
        if (lane == 0) sp[wave] = t;
        __syncthreads();
        if (tid == 0)
            out[0] = -(sp[0] + sp[1] + sp[2] + sp[3]) * (1.0f / (float)BB);
    }
}

extern "C" void kernel_launch(void* const* d_in, const int* in_sizes, int n_in,
                              void* d_out, int out_size, void* d_ws, size_t ws_size,
                              hipStream_t stream) {
    const int*   context = (const int*)d_in[0];
    const int*   target  = (const int*)d_in[1];
    const int*   negs    = (const int*)d_in[2];
    const float* embW    = (const float*)d_in[3];
    const float* ctxW    = (const float*)d_in[4];
    float* out = (float*)d_out;

    float*        block_part = (float*)d_ws;                 // 2048 floats
    unsigned int* ticket     = (unsigned int*)((char*)d_ws + NBLOCKS * sizeof(float));

    // zero the ticket every call (graph-safe async memset on the stream)
    hipMemsetAsync(ticket, 0, sizeof(unsigned int), stream);

    w2v_loss_kernel<<<NBLOCKS, 256, 0, stream>>>(
        context, target, negs, embW, ctxW, block_part, ticket, out);
}